// Round 5
// baseline (3001.184 us; speedup 1.0000x reference)
//
#include <hip/hip_runtime.h>
#include <hip/hip_bf16.h>
#include <math.h>

#define VOCAB  32000
#define EMBED  256
#define HIDDEN 512
#define BATCH  64
#define TCAP   32
#define SEQ    33      // T_CAP + 1
#define G4     2048    // 4 * HIDDEN
#define MROWS  2112    // BATCH * SEQ
#define NBLK_LSTM 256

typedef unsigned short ushort_t;

__device__ __forceinline__ float bf2f(ushort_t u) {
    union { unsigned int i; float f; } v;
    v.i = ((unsigned int)u) << 16;
    return v.f;
}

__device__ __forceinline__ void bfpair(unsigned int u, float& lo, float& hi) {
    union { unsigned int i; float f; } a, b;
    a.i = u << 16;
    b.i = u & 0xffff0000u;
    lo = a.f; hi = b.f;
}

// load 8 consecutive weights (either dtype) as fp32
template<bool BF>
__device__ __forceinline__ void ldw8(const void* p, size_t idx, float* w) {
    if constexpr (BF) {
        uint4 u = *(const uint4*)((const ushort_t*)p + idx);
        bfpair(u.x, w[0], w[1]); bfpair(u.y, w[2], w[3]);
        bfpair(u.z, w[4], w[5]); bfpair(u.w, w[6], w[7]);
    } else {
        float4 a = *(const float4*)((const float*)p + idx);
        float4 b = *(const float4*)((const float*)p + idx + 4);
        w[0]=a.x; w[1]=a.y; w[2]=a.z; w[3]=a.w;
        w[4]=b.x; w[5]=b.y; w[6]=b.z; w[7]=b.w;
    }
}

template<bool BF>
__device__ __forceinline__ float ldw1(const void* p, size_t i) {
    if constexpr (BF) return bf2f(((const ushort_t*)p)[i]);
    else return ((const float*)p)[i];
}

__device__ __forceinline__ float dot8f(const float* w, const float* h) {
    return w[0]*h[0]+w[1]*h[1]+w[2]*h[2]+w[3]*h[3]
         + w[4]*h[4]+w[5]*h[5]+w[6]*h[6]+w[7]*h[7];
}

__device__ __forceinline__ float sigm(float x) { return 1.0f / (1.0f + expf(-x)); }

// ---------------------------------------------------------------------------
// Grid barrier: monotonic-generation, device-scope. Counters in workspace,
// zeroed by k_detect each launch/replay. All NBLK_LSTM blocks co-resident
// (256 blocks x 4 waves, 10KB LDS -> fits trivially on 256 CUs).
// ---------------------------------------------------------------------------
__device__ __forceinline__ void gridbar(unsigned* cnt, unsigned* gen) {
    __syncthreads();
    if (threadIdx.x == 0) {
        __builtin_amdgcn_fence(__ATOMIC_SEQ_CST, "agent");   // release: wb L2
        unsigned g = __hip_atomic_load(gen, __ATOMIC_RELAXED, __HIP_MEMORY_SCOPE_AGENT);
        unsigned old = __hip_atomic_fetch_add(cnt, 1u, __ATOMIC_ACQ_REL, __HIP_MEMORY_SCOPE_AGENT);
        if (old == NBLK_LSTM - 1u) {
            __hip_atomic_store(cnt, 0u, __ATOMIC_RELAXED, __HIP_MEMORY_SCOPE_AGENT);
            __hip_atomic_fetch_add(gen, 1u, __ATOMIC_ACQ_REL, __HIP_MEMORY_SCOPE_AGENT);
        } else {
            while (__hip_atomic_load(gen, __ATOMIC_ACQUIRE, __HIP_MEMORY_SCOPE_AGENT) == g)
                __builtin_amdgcn_s_sleep(8);
        }
        __builtin_amdgcn_fence(__ATOMIC_SEQ_CST, "agent");   // acquire: inv L1/L2
    }
    __syncthreads();
}

// ---------------------------------------------------------------------------
// Dtype detector + barrier-counter reset (runs first every launch/replay)
// ---------------------------------------------------------------------------
__global__ void k_detect(const unsigned int* __restrict__ w, int* __restrict__ mode,
                         unsigned* __restrict__ bar) {
    __shared__ int cnt[256];
    int c = 0;
    for (int i = threadIdx.x; i < 8192; i += 256) {
        unsigned int lo = w[i] & 0xffffu;
        int e = (lo >> 7) & 0xff;
        if (e >= 113 && e <= 131) c++;
    }
    cnt[threadIdx.x] = c;
    __syncthreads();
    for (int s = 128; s > 0; s >>= 1) {
        if (threadIdx.x < s) cnt[threadIdx.x] += cnt[threadIdx.x + s];
        __syncthreads();
    }
    if (threadIdx.x == 0) {
        *mode = (cnt[0] > 6000) ? 1 : 0;   // 1 = bf16
        __hip_atomic_store(bar + 0, 0u, __ATOMIC_RELAXED, __HIP_MEMORY_SCOPE_AGENT);
        __hip_atomic_store(bar + 1, 0u, __ATOMIC_RELAXED, __HIP_MEMORY_SCOPE_AGENT);
    }
}

// ---------------------------------------------------------------------------
// K1 v2: xp[bt][g] = dot(x_bt, W_ih[g]) + b_ih[g] + b_hh[g]
// Runtime-mode (single launch). grid (8, 2112), block 256.
// ---------------------------------------------------------------------------
__global__ void k_xproj2(const int* __restrict__ mode,
                         const void* __restrict__ features,
                         const int*  __restrict__ captions,
                         const void* __restrict__ embedding,
                         const void* __restrict__ W_ih,
                         const void* __restrict__ b_ih,
                         const void* __restrict__ b_hh,
                         float* __restrict__ xp) {
    const bool bf = (*mode != 0);
    __shared__ float xs[EMBED];
    int bt  = blockIdx.y;
    int b   = bt / SEQ;
    int t   = bt % SEQ;
    int tid = threadIdx.x;

    size_t src_off;
    const void* src;
    if (t == 0) { src = features;  src_off = (size_t)b * EMBED; }
    else        { src = embedding; src_off = (size_t)captions[b * TCAP + (t - 1)] * EMBED; }
    xs[tid] = bf ? bf2f(((const ushort_t*)src)[src_off + tid])
                 : ((const float*)src)[src_off + tid];
    __syncthreads();

    int g = blockIdx.x * 256 + tid;
    float acc;
    size_t wbase = (size_t)g * EMBED;
    if (bf) {
        acc = bf2f(((const ushort_t*)b_ih)[g]) + bf2f(((const ushort_t*)b_hh)[g]);
        for (int e = 0; e < EMBED; e += 8) {
            float w[8];
            ldw8<true>(W_ih, wbase + e, w);
            acc += dot8f(w, xs + e);
        }
    } else {
        acc = ((const float*)b_ih)[g] + ((const float*)b_hh)[g];
        for (int e = 0; e < EMBED; e += 8) {
            float w[8];
            ldw8<false>(W_ih, wbase + e, w);
            acc += dot8f(w, xs + e);
        }
    }
    xp[(size_t)bt * G4 + g] = acc;
}

// ---------------------------------------------------------------------------
// W_hh repack (unchanged): k-blocked so lstm's lane-j loads are coalesced.
// fp32: WT4[k>>2][g][k&3]; bf16: WT8[k>>3][g][k&7]
// ---------------------------------------------------------------------------
__global__ void k_wtr(const int* __restrict__ mode,
                      const void* __restrict__ Whh,
                      void* __restrict__ WT) {
    const bool bf = (*mode != 0);
    for (int r = 0; r < 4; r++) {
        size_t e = (size_t)blockIdx.x * 1024 + r * 256 + threadIdx.x;
        int g = (int)(e >> 9);
        int k = (int)(e & 511);
        if (bf) {
            ushort_t w = ((const ushort_t*)Whh)[e];
            ((ushort_t*)WT)[((size_t)(k >> 3) << 14) + ((size_t)g << 3) + (k & 7)] = w;
        } else {
            float w = ((const float*)Whh)[e];
            ((float*)WT)[((size_t)(k >> 2) << 13) + ((size_t)g << 2) + (k & 3)] = w;
        }
    }
}

// ---------------------------------------------------------------------------
// K2 v4: PERSISTENT LSTM — all 33 steps in one launch, grid-synced.
// 256 blocks x 256 thr = k_step3's (16,16) grid flattened; identical inner
// loops (split-K kh, WT loads, hsh staging). c lives in a register (block
// owns (b,j) across t). One gridbar per step boundary.
// ---------------------------------------------------------------------------
__global__ __launch_bounds__(256)
void k_lstm(const int* __restrict__ mode,
            const float* __restrict__ xp,
            const void* __restrict__ WT,
            float* __restrict__ hs,
            unsigned* __restrict__ bar) {
    const bool bf = (*mode != 0);
    __shared__ float hsh[4][HIDDEN];      // 8 KB
    __shared__ float psum[4][32][4];      // 2 KB
    int tid = threadIdx.x;
    int jl = tid & 31;
    int bb = (tid >> 5) & 3;
    int kh = tid >> 7;                    // 0 or 1
    int blk = blockIdx.x;                 // 0..255
    int bx = blk & 15, by = blk >> 4;
    int j  = bx * 32 + jl;
    int b  = by * 4 + bb;
    float c_reg = 0.0f;

    for (int t = 0; t < SEQ; ++t) {
        if (t > 0) {
            gridbar(bar + 0, bar + 1);    // step t-1's hs writes visible
            for (int r = 0; r < 2; r++) {
                int i4 = tid + r * 256;
                int sb = i4 >> 7, k4 = (i4 & 127) << 2;
                *(float4*)(&hsh[sb][k4]) =
                    *(const float4*)(hs + ((size_t)(by * 4 + sb) * SEQ + (t - 1)) * HIDDEN + k4);
            }
            __syncthreads();
        }

        float ai = 0.f, af = 0.f, ag = 0.f, ao = 0.f;

        if (t > 0) {
            const float* hp = hsh[bb];
            if (bf) {
                const ushort_t* wt = (const ushort_t*)WT;
                const ushort_t* p0 = wt + (size_t)j * 8;
                const ushort_t* p1 = wt + (size_t)(HIDDEN + j) * 8;
                const ushort_t* p2 = wt + (size_t)(2 * HIDDEN + j) * 8;
                const ushort_t* p3 = wt + (size_t)(3 * HIDDEN + j) * 8;
#pragma unroll 2
                for (int k8 = kh * 32; k8 < kh * 32 + 32; ++k8) {
                    size_t pb = (size_t)k8 * 16384;
                    uint4 u0 = *(const uint4*)(p0 + pb);
                    uint4 u1 = *(const uint4*)(p1 + pb);
                    uint4 u2 = *(const uint4*)(p2 + pb);
                    uint4 u3 = *(const uint4*)(p3 + pb);
                    float4 h0 = *(const float4*)(hp + k8 * 8);
                    float4 h1 = *(const float4*)(hp + k8 * 8 + 4);
                    float w[8];
                    bfpair(u0.x, w[0], w[1]); bfpair(u0.y, w[2], w[3]);
                    bfpair(u0.z, w[4], w[5]); bfpair(u0.w, w[6], w[7]);
                    ai += w[0]*h0.x + w[1]*h0.y + w[2]*h0.z + w[3]*h0.w
                        + w[4]*h1.x + w[5]*h1.y + w[6]*h1.z + w[7]*h1.w;
                    bfpair(u1.x, w[0], w[1]); bfpair(u1.y, w[2], w[3]);
                    bfpair(u1.z, w[4], w[5]); bfpair(u1.w, w[6], w[7]);
                    af += w[0]*h0.x + w[1]*h0.y + w[2]*h0.z + w[3]*h0.w
                        + w[4]*h1.x + w[5]*h1.y + w[6]*h1.z + w[7]*h1.w;
                    bfpair(u2.x, w[0], w[1]); bfpair(u2.y, w[2], w[3]);
                    bfpair(u2.z, w[4], w[5]); bfpair(u2.w, w[6], w[7]);
                    ag += w[0]*h0.x + w[1]*h0.y + w[2]*h0.z + w[3]*h0.w
                        + w[4]*h1.x + w[5]*h1.y + w[6]*h1.z + w[7]*h1.w;
                    bfpair(u3.x, w[0], w[1]); bfpair(u3.y, w[2], w[3]);
                    bfpair(u3.z, w[4], w[5]); bfpair(u3.w, w[6], w[7]);
                    ao += w[0]*h0.x + w[1]*h0.y + w[2]*h0.z + w[3]*h0.w
                        + w[4]*h1.x + w[5]*h1.y + w[6]*h1.z + w[7]*h1.w;
                }
            } else {
                const float* wt = (const float*)WT;
                const float* p0 = wt + (size_t)j * 4;
                const float* p1 = wt + (size_t)(HIDDEN + j) * 4;
                const float* p2 = wt + (size_t)(2 * HIDDEN + j) * 4;
                const float* p3 = wt + (size_t)(3 * HIDDEN + j) * 4;
#pragma unroll 4
                for (int k4 = kh * 64; k4 < kh * 64 + 64; ++k4) {
                    size_t pb = (size_t)k4 * 8192;
                    float4 wi = *(const float4*)(p0 + pb);
                    float4 wf = *(const float4*)(p1 + pb);
                    float4 wg = *(const float4*)(p2 + pb);
                    float4 wo = *(const float4*)(p3 + pb);
                    float4 hv = *(const float4*)(hp + k4 * 4);
                    ai += wi.x*hv.x + wi.y*hv.y + wi.z*hv.z + wi.w*hv.w;
                    af += wf.x*hv.x + wf.y*hv.y + wf.z*hv.z + wf.w*hv.w;
                    ag += wg.x*hv.x + wg.y*hv.y + wg.z*hv.z + wg.w*hv.w;
                    ao += wo.x*hv.x + wo.y*hv.y + wo.z*hv.z + wo.w*hv.w;
                }
            }
            if (kh == 1) {
                psum[bb][jl][0] = ai; psum[bb][jl][1] = af;
                psum[bb][jl][2] = ag; psum[bb][jl][3] = ao;
            }
            __syncthreads();
            if (kh == 0) {
                ai += psum[bb][jl][0]; af += psum[bb][jl][1];
                ag += psum[bb][jl][2]; ao += psum[bb][jl][3];
            }
        }

        if (kh == 0) {
            size_t xbase = ((size_t)b * SEQ + t) * G4;
            ai += xp[xbase + j];
            af += xp[xbase + HIDDEN + j];
            ag += xp[xbase + 2 * HIDDEN + j];
            ao += xp[xbase + 3 * HIDDEN + j];

            float c = sigm(af) * c_reg + sigm(ai) * tanhf(ag);
            float h = sigm(ao) * tanhf(c);
            c_reg = c;
            hs[((size_t)b * SEQ + t) * HIDDEN + j] = h;
        }
        // barrier for these writes happens at top of next iteration
    }
}

// ---------------------------------------------------------------------------
// K2 fallback (old, W_hh direct) — only if workspace too small for WT.
// ---------------------------------------------------------------------------
template<bool BF>
__global__ void k_step(const int* __restrict__ mode,
                       const float* __restrict__ xp,
                       const void* __restrict__ W_hh,
                       float* __restrict__ c_buf,
                       float* __restrict__ hs,
                       int t) {
    if (*mode != (int)BF) return;
    __shared__ float hsh[4][HIDDEN];
    int tid = threadIdx.x;
    int jl  = tid & 63, bb = tid >> 6;
    int j   = blockIdx.x * 64 + jl;
    int b   = blockIdx.y * 4 + bb;

    if (t > 0) {
        for (int r = 0; r < 2; r++) {
            int i4 = tid + r * 256;
            int sb = i4 >> 7, k4 = (i4 & 127) << 2;
            *(float4*)(&hsh[sb][k4]) =
                *(const float4*)(hs + ((size_t)(blockIdx.y * 4 + sb) * SEQ + (t - 1)) * HIDDEN + k4);
        }
        __syncthreads();
    }

    size_t xbase = ((size_t)b * SEQ + t) * G4;
    float ai = xp[xbase + j];
    float af = xp[xbase + HIDDEN + j];
    float ag = xp[xbase + 2 * HIDDEN + j];
    float ao = xp[xbase + 3 * HIDDEN + j];

    if (t > 0) {
        const float* hp = hsh[bb];
        size_t r0 = (size_t)j * HIDDEN;
        size_t r1 = (size_t)(HIDDEN + j) * HIDDEN;
        size_t r2 = (size_t)(2 * HIDDEN + j) * HIDDEN;
        size_t r3 = (size_t)(3 * HIDDEN + j) * HIDDEN;
        for (int k = 0; k < HIDDEN; k += 8) {
            float w[8];
            ldw8<BF>(W_hh, r0 + k, w); ai += dot8f(w, hp + k);
            ldw8<BF>(W_hh, r1 + k, w); af += dot8f(w, hp + k);
            ldw8<BF>(W_hh, r2 + k, w); ag += dot8f(w, hp + k);
            ldw8<BF>(W_hh, r3 + k, w); ao += dot8f(w, hp + k);
        }
    }

    float c_prev = (t > 0) ? c_buf[b * HIDDEN + j] : 0.0f;
    float c = sigm(af) * c_prev + sigm(ai) * tanhf(ag);
    float h = sigm(ao) * tanhf(c);
    c_buf[b * HIDDEN + j] = c;
    hs[((size_t)b * SEQ + t) * HIDDEN + j] = h;
}

// ---------------------------------------------------------------------------
// K3 (unchanged from R4): 128x128x32 SGEMM, XOR-swizzled LDS, XCD-chunked.
// ---------------------------------------------------------------------------
#define BM 128
#define BN 128
#define KC 32
#define NBN 250              // 32000 / 128
#define NBM 17               // ceil(2112 / 128)
#define LOGITS_GRID (8 * 32 * NBM)   // 4352

__device__ __forceinline__ int swz(int r) {   // bijective on 0..127
    return ((r >> 2) & 1) * 64 + (r >> 3) * 4 + (r & 3);
}

template<bool BF>
__global__ __launch_bounds__(256, 4)
void k_logits(const int* __restrict__ mode,
              const float* __restrict__ hs,
              const void* __restrict__ W_out,
              const void* __restrict__ b_out,
              void* __restrict__ out) {
    if (*mode != (int)BF) return;

    int bid = blockIdx.x;
    int xcd = bid & 7;
    int j8  = bid >> 3;
    int mb  = j8 % NBM;
    int nb  = xcd + 8 * (j8 / NBM);
    if (nb >= NBN) return;

    __shared__ float As[KC][BM];
    __shared__ float Bs[KC][BN];

    int t  = threadIdx.x;
    int tm = t >> 4;               // 0..15
    int tn = t & 15;               // 0..15
    int m_base = mb * BM;
    int n_base = nb * BN;

    float acc[8][8];
#pragma unroll
    for (int i = 0; i < 8; ++i)
#pragma unroll
        for (int q = 0; q < 8; ++q) acc[i][q] = 0.0f;

    for (int kt = 0; kt < HIDDEN / KC; ++kt) {
        __syncthreads();

        // ---- stage A (hs): 128x32 f32, coalesced float4 row-chunk loads ----
#pragma unroll
        for (int i = 0; i < 4; ++i) {
            int flat = t + i * 256;        // float4 id 0..1023
            int m  = flat >> 3;            // 0..127
            int kq = flat & 7;             // 0..7
            int gm = m_base + m;
            float4 v = make_float4(0.f, 0.f, 0.f, 0.f);
            if (gm < MROWS)
                v = *(const float4*)(hs + (size_t)gm * HIDDEN + kt * KC + kq * 4);
            int col = swz(m) ^ (kq << 2);
            As[kq*4+0][col] = v.x; As[kq*4+1][col] = v.y;
            As[kq*4+2][col] = v.z; As[kq*4+3][col] = v.w;
        }

        // ---- stage B (W_out): 128x32, dtype-dependent vector loads ----
        if constexpr (BF) {
#pragma unroll
            for (int i = 0; i < 2; ++i) {
                int flat = t + i * 256;    // uint4 id 0..511 (8 bf16 each)
                int n  = flat >> 2;        // 0..127
                int ko = (flat & 3) * 8;   // 0,8,16,24
                const ushort_t* src = (const ushort_t*)W_out
                    + (size_t)(n_base + n) * HIDDEN + kt * KC + ko;
                uint4 u = *(const uint4*)src;
                float w[8];
                bfpair(u.x, w[0], w[1]); bfpair(u.y, w[2], w[3]);
                bfpair(u.z, w[4], w[5]); bfpair(u.w, w[6], w[7]);
                int sb = swz(n);
#pragma unroll
                for (int d = 0; d < 8; ++d) {
                    int kq = (ko + d) >> 2;
                    Bs[ko + d][sb ^ (kq << 2)] = w[d];
                }
            }
        } else {
#pragma unroll
            for (int i = 0; i < 4; ++i) {
                int flat = t + i * 256;
                int n  = flat >> 3;
                int kq = flat & 7;
                const float* src = (const float*)W_out
                    + (size_t)(n_base + n) * HIDDEN + kt * KC + kq * 4;
                float4 v = *(const float4*)src;
                int col = swz(n) ^ (kq << 2);
                Bs[kq*4+0][col] = v.x; Bs[kq*4+1][col] = v.y;
                Bs[kq*4+2][col] = v.z; Bs[kq*4+3][col] = v.w;
            }
        }
        __syncthreads();

        // ---- inner: 32 k-steps, 64 FMA per 4 ds_read_b128 (conflict-free) --
#pragma unroll 8
        for (int k = 0; k < KC; ++k) {
            int kx = k & 28;               // (k>>2)<<2
            float4 a0 = *(const float4*)&As[k][(tm * 4) ^ kx];
            float4 a1 = *(const float4*)&As[k][64 + ((tm * 4) ^ kx)];
            float4 b0 = *(const float4*)&Bs[k][(tn * 4) ^ kx];
            float4 b1 = *(const float4*)&Bs[k][64 + ((tn * 4) ^ kx)];
            float a[8] = {a0.x, a0.y, a0.z, a0.w, a1.x, a1.y, a1.z, a1.w};
            float b[8] = {b0.x, b0.y, b0.z, b0.w, b1.x, b1.y, b1.z, b1.w};
#pragma unroll
            for (int i = 0; i < 8; ++i)
#pragma unroll
                for (int q = 0; q < 8; ++q)
                    acc[i][q] = fmaf(a[i], b[q], acc[i][q]);
        }
    }

    // ---- epilogue: thread owns m=8tm+i, n=8tn+q ----
    float bias[8];
#pragma unroll
    for (int q = 0; q < 8; ++q) bias[q] = ldw1<BF>(b_out, n_base + tn * 8 + q);

#pragma unroll
    for (int i = 0; i < 8; ++i) {
        int gm = m_base + tm * 8 + i;
        if (gm >= MROWS) continue;
        size_t o = (size_t)gm * VOCAB + n_base + tn * 8;
        if constexpr (BF) {
            unsigned int p[4];
#pragma unroll
            for (int q = 0; q < 4; ++q) {
                __hip_bfloat16 lo = __float2bfloat16(acc[i][2*q]   + bias[2*q]);
                __hip_bfloat16 hi = __float2bfloat16(acc[i][2*q+1] + bias[2*q+1]);
                unsigned short ul = *(unsigned short*)&lo;
                unsigned short uh = *(unsigned short*)&hi;
                p[q] = (unsigned int)ul | ((unsigned int)uh << 16);
            }
            *(uint4*)((__hip_bfloat16*)out + o) = make_uint4(p[0], p[1], p[2], p[3]);
        } else {
            float* op = (float*)out + o;
            *(float4*)(op + 0) = make_float4(acc[i][0]+bias[0], acc[i][1]+bias[1],
                                             acc[i][2]+bias[2], acc[i][3]+bias[3]);
            *(float4*)(op + 4) = make_float4(acc[i][4]+bias[4], acc[i][5]+bias[5],
                                             acc[i][6]+bias[6], acc[i][7]+bias[7]);
        }
    }
}

// ---------------------------------------------------------------------------
extern "C" void kernel_launch(void* const* d_in, const int* in_sizes, int n_in,
                              void* d_out, int out_size, void* d_ws, size_t ws_size,
                              hipStream_t stream) {
    const void* features  = d_in[0];
    const int*  captions  = (const int*)d_in[1];
    const void* embedding = d_in[3];
    const void* W_ih      = d_in[4];
    const void* W_hh      = d_in[5];
    const void* b_ih      = d_in[6];
    const void* b_hh      = d_in[7];
    const void* W_out     = d_in[8];
    const void* b_out     = d_in[9];

    // ws layout: xp[2112][2048] f32 | hs[2112][512] f32 | c_buf[64][512] f32 |
    //            mode (int) + bar[2] (in the 16B pad) | WT (4MB repacked W_hh)
    char* ws = (char*)d_ws;
    const size_t XP_OFF = 0;
    const size_t HS_OFF = (size_t)2112 * G4 * 4;
    const size_t CB_OFF = HS_OFF + (size_t)2112 * HIDDEN * 4;
    const size_t MODE_OFF = CB_OFF + (size_t)BATCH * HIDDEN * 4;
    const size_t WT_OFF = MODE_OFF + 16;
    const size_t NEED = WT_OFF + (size_t)4 * 1024 * 1024;

    float* xp    = (float*)(ws + XP_OFF);
    float* hs    = (float*)(ws + HS_OFF);
    float* c_buf = (float*)(ws + CB_OFF);
    int*   mode  = (int*)(ws + MODE_OFF);
    unsigned* bar = (unsigned*)(ws + MODE_OFF + 8);
    void*  WT    = (void*)(ws + WT_OFF);

    const bool fast = (ws_size >= NEED);

    k_detect<<<1, 256, 0, stream>>>((const unsigned int*)features, mode, bar);

    if (fast)
        k_wtr<<<1024, 256, 0, stream>>>(mode, W_hh, WT);

    k_xproj2<<<dim3(8, BATCH * SEQ), 256, 0, stream>>>(
        mode, features, captions, embedding, W_ih, b_ih, b_hh, xp);

    if (fast) {
        k_lstm<<<NBLK_LSTM, 256, 0, stream>>>(mode, xp, WT, hs, bar);
    } else {
        for (int t = 0; t < SEQ; t++) {
            k_step<false><<<dim3(8, BATCH / 4), 256, 0, stream>>>(mode, xp, W_hh, c_buf, hs, t);
            k_step<true><<<dim3(8, BATCH / 4), 256, 0, stream>>>(mode, xp, W_hh, c_buf, hs, t);
        }
    }

    k_logits<false><<<dim3(LOGITS_GRID), 256, 0, stream>>>(mode, hs, W_out, b_out, d_out);
    k_logits<true><<<dim3(LOGITS_GRID), 256, 0, stream>>>(mode, hs, W_out, b_out, d_out);
}